// Round 1
// 459.703 us; speedup vs baseline: 1.0107x; 1.0107x over previous
//
#include <hip/hip_runtime.h>
#include <math.h>

#define NN 8192
// out = elu(0.5*h_s + (sum_j w_ij h_n_j)/Z_i), w_ij = adj_ij * exp(relu(s_i+n_j))

typedef short short8 __attribute__((ext_vector_type(8)));   // 8 bf16 (4 VGPRs)
typedef float f32x4 __attribute__((ext_vector_type(4)));

__device__ __forceinline__ float eluf(float x) {
  return x > 0.f ? x : (__expf(x) - 1.f);
}
__device__ __forceinline__ unsigned short f2bf(float f) {
  union { float f; unsigned u; } v; v.f = f;
  unsigned r = v.u + 0x7fffu + ((v.u >> 16) & 1u);  // RNE
  return (unsigned short)(r >> 16);
}

// ---------------- Kernel 1: projections + fused s/n reductions ----------------
// 8 rows/block, block 256, grid 1024. Unchanged except HnT output layout:
// now j-block-major [NN/8][128 f][8 j] bf16 so k_main's 8 B-frag loads per
// 32-j step share ONE lane base + imm offsets (0..1792B) and coalesce to
// 256B segments per quad.
__global__ __launch_bounds__(256) void k_proj(const float* __restrict__ X,
                                              const float* __restrict__ Ws,
                                              const float* __restrict__ Wn,
                                              const float* __restrict__ as_,
                                              const float* __restrict__ an_,
                                              float* __restrict__ Hs,
                                              unsigned short* __restrict__ HnT,
                                              float* __restrict__ s_out,
                                              float* __restrict__ n_out) {
  __shared__ float4 lin4[8 * 64];  // 8 rows x 256 f32 = 8 KB
  const int t = threadIdx.x;
  const int i0 = blockIdx.x * 8;
  const float4* Xg = (const float4*)X + (size_t)i0 * 64;
  lin4[t] = Xg[t];
  if (t < 256) lin4[t + 256] = Xg[t + 256];
  __syncthreads();
  const int c = t & 127;
  const int rh = t >> 7;  // 0..1, 4 rows each
  float accs[4], accn[4];
#pragma unroll
  for (int r = 0; r < 4; ++r) { accs[r] = 0.f; accn[r] = 0.f; }
  for (int k = 0; k < 256; k += 4) {
    float ws0 = Ws[(k + 0) * 128 + c], ws1 = Ws[(k + 1) * 128 + c];
    float ws2 = Ws[(k + 2) * 128 + c], ws3 = Ws[(k + 3) * 128 + c];
    float wn0 = Wn[(k + 0) * 128 + c], wn1 = Wn[(k + 1) * 128 + c];
    float wn2 = Wn[(k + 2) * 128 + c], wn3 = Wn[(k + 3) * 128 + c];
#pragma unroll
    for (int r = 0; r < 4; ++r) {
      float4 iv = lin4[(rh * 4 + r) * 64 + (k >> 2)];  // wave-uniform broadcast
      accs[r] = fmaf(iv.x, ws0, accs[r]); accs[r] = fmaf(iv.y, ws1, accs[r]);
      accs[r] = fmaf(iv.z, ws2, accs[r]); accs[r] = fmaf(iv.w, ws3, accs[r]);
      accn[r] = fmaf(iv.x, wn0, accn[r]); accn[r] = fmaf(iv.y, wn1, accn[r]);
      accn[r] = fmaf(iv.z, wn2, accn[r]); accn[r] = fmaf(iv.w, wn3, accn[r]);
    }
  }
  // Hs fp32 out
#pragma unroll
  for (int r = 0; r < 4; ++r)
    Hs[(size_t)(i0 + rh * 4 + r) * 128 + c] = accs[r];
  // HnT bf16 out, j-block-major: elem(jb=j/8, f, ji=j%8) at jb*1024 + f*8 + ji.
  // Here j = i0 + rh*4 + r -> jb = blockIdx.x, ji = rh*4+r.
  {
    union { unsigned short us[4]; ushort4 u4; } pk;
#pragma unroll
    for (int r = 0; r < 4; ++r) pk.us[r] = f2bf(accn[r]);
    *(ushort4*)(HnT + (size_t)blockIdx.x * 1024 + c * 8 + rh * 4) = pk.u4;
  }
  // ---- fused reductions: s[j] = sum_f Hs[j][f]*a_s[f], n likewise ----
  float* red = (float*)lin4;  // 8 x 128 f32 = 4 KB
  const int wv = t >> 6, ln = t & 63;
  __syncthreads();
  {
    float av = as_[c];
#pragma unroll
    for (int r = 0; r < 4; ++r) red[(rh * 4 + r) * 128 + c] = accs[r] * av;
  }
  __syncthreads();
#pragma unroll
  for (int h = 0; h < 2; ++h) {
    int row = wv * 2 + h;
    float p = red[row * 128 + ln] + red[row * 128 + 64 + ln];
#pragma unroll
    for (int off = 32; off >= 1; off >>= 1) p += __shfl_down(p, off);
    if (ln == 0) s_out[i0 + row] = p;
  }
  __syncthreads();
  {
    float av = an_[c];
#pragma unroll
    for (int r = 0; r < 4; ++r) red[(rh * 4 + r) * 128 + c] = accn[r] * av;
  }
  __syncthreads();
#pragma unroll
  for (int h = 0; h < 2; ++h) {
    int row = wv * 2 + h;
    float p = red[row * 128 + ln] + red[row * 128 + 64 + ln];
#pragma unroll
    for (int off = 32; off >= 1; off >>= 1) p += __shfl_down(p, off);
    if (ln == 0) n_out[i0 + row] = p;
  }
}

// ---------------- Kernel 2: fused attention GEMM (bf16 MFMA) + softmax + elu --------
// Barrier-free main loop: 16 rows/block, block 512 (8 waves), grid 512
// (2 blocks/CU = 16 waves/CU; __launch_bounds__(512,4) caps VGPR at 128).
// Each wave owns a private 1024-wide j-range (32 steps of K=32), computes its
// A-frag (w = adj*exp(relu(s+n))) entirely in registers, and runs all 8
// f-tiles of MFMA itself (acc = 16x128/wave). No LDS, no __syncthreads in the
// loop -> 8 fully independent instruction streams per block for latency hiding.
// Per-step source issue order: compute -> nv(t+1) -> MFMA -> breg(t+1) ->
// adj(t+2), so FIFO vmcnt waits never force-drain the 2-step adj prefetch.
// Cross-wave partials combined once at the end via a 64 KB LDS reduction.
__global__ __launch_bounds__(512, 4) void k_main(const int* __restrict__ A,
                                                 const unsigned short* __restrict__ HnT,
                                                 const float* __restrict__ sv_g,
                                                 const float* __restrict__ nv_g,
                                                 float* __restrict__ HsOut) {
  __shared__ float accbuf[8][16][128];  // 64 KB: per-wave 16x128 partials
  __shared__ float zsh[8][16];
  __shared__ float zf[16];

  const int t = threadIdx.x;
  const int wv = t >> 6;   // wave 0..7 = j-partition
  const int ln = t & 63;
  const int q = ln >> 4;   // quad -> k-slice within K=32
  const int m = ln & 15;   // A row / B col / C col
  const int row0 = blockIdx.x * 16;

  const float sm = sv_g[row0 + m];
  const int jbase = wv * 1024 + q * 8;
  const int* aptr = A + (size_t)(row0 + m) * NN + jbase;
  const float* nptr = nv_g + jbase;
  // HnT elem(jb, f, ji) at jb*1024 + f*8 + ji ; lane base: jb = wv*128 + q, f = m
  const unsigned short* bptr = HnT + ((size_t)(wv * 128 + q) * 128 + m) * 8;

  f32x4 acc[8];
#pragma unroll
  for (int ft = 0; ft < 8; ++ft) acc[ft] = (f32x4){0.f, 0.f, 0.f, 0.f};
  float zp = 0.f;

  int4 adjv[2][2];
  float4 nvv[2][2];
  union Breg { uint4 u; short8 s; };
  Breg breg[8];

  // prolog: adj(0), adj(1), nv(0), breg(0)
  adjv[0][0] = *(const int4*)(aptr);       adjv[0][1] = *(const int4*)(aptr + 4);
  adjv[1][0] = *(const int4*)(aptr + 32);  adjv[1][1] = *(const int4*)(aptr + 36);
  nvv[0][0] = *(const float4*)(nptr);      nvv[0][1] = *(const float4*)(nptr + 4);
  breg[0].u = *(const uint4*)(bptr);       breg[1].u = *(const uint4*)(bptr + 128);
  breg[2].u = *(const uint4*)(bptr + 256); breg[3].u = *(const uint4*)(bptr + 384);
  breg[4].u = *(const uint4*)(bptr + 512); breg[5].u = *(const uint4*)(bptr + 640);
  breg[6].u = *(const uint4*)(bptr + 768); breg[7].u = *(const uint4*)(bptr + 896);

#pragma unroll 2
  for (int tt = 0; tt < 32; ++tt) {
    const int cur = tt & 1;
    // ---- A-frag: w for rows m, j = jbase + tt*32 + q*8 .. +7 ----
    short8 fr;
    {
      float nvl[8] = {nvv[cur][0].x, nvv[cur][0].y, nvv[cur][0].z, nvv[cur][0].w,
                      nvv[cur][1].x, nvv[cur][1].y, nvv[cur][1].z, nvv[cur][1].w};
      int av[8] = {adjv[cur][0].x, adjv[cur][0].y, adjv[cur][0].z, adjv[cur][0].w,
                   adjv[cur][1].x, adjv[cur][1].y, adjv[cur][1].z, adjv[cur][1].w};
#pragma unroll
      for (int k = 0; k < 8; ++k) {
        float w = av[k] > 0 ? __expf(fmaxf(sm + nvl[k], 0.f)) : 0.f;
        zp += w;
        fr[k] = (short)f2bf(w);
      }
    }
    // ---- issue nv(tt+1) ----
    if (tt < 31) {
      const float* p = nptr + (tt + 1) * 32;
      nvv[cur ^ 1][0] = *(const float4*)p;
      nvv[cur ^ 1][1] = *(const float4*)(p + 4);
    }
    // ---- MFMA: consumes breg(tt) issued last step; adj/nv stay in flight ----
    __builtin_amdgcn_s_setprio(1);
    acc[0] = __builtin_amdgcn_mfma_f32_16x16x32_bf16(fr, breg[0].s, acc[0], 0, 0, 0);
    acc[1] = __builtin_amdgcn_mfma_f32_16x16x32_bf16(fr, breg[1].s, acc[1], 0, 0, 0);
    acc[2] = __builtin_amdgcn_mfma_f32_16x16x32_bf16(fr, breg[2].s, acc[2], 0, 0, 0);
    acc[3] = __builtin_amdgcn_mfma_f32_16x16x32_bf16(fr, breg[3].s, acc[3], 0, 0, 0);
    acc[4] = __builtin_amdgcn_mfma_f32_16x16x32_bf16(fr, breg[4].s, acc[4], 0, 0, 0);
    acc[5] = __builtin_amdgcn_mfma_f32_16x16x32_bf16(fr, breg[5].s, acc[5], 0, 0, 0);
    acc[6] = __builtin_amdgcn_mfma_f32_16x16x32_bf16(fr, breg[6].s, acc[6], 0, 0, 0);
    acc[7] = __builtin_amdgcn_mfma_f32_16x16x32_bf16(fr, breg[7].s, acc[7], 0, 0, 0);
    __builtin_amdgcn_s_setprio(0);
    // ---- issue breg(tt+1): 8 f-tiles, one base + imm offsets ----
    if (tt < 31) {
      const unsigned short* p = bptr + (size_t)(tt + 1) * 4096;  // +4 j-blocks
      breg[0].u = *(const uint4*)(p);       breg[1].u = *(const uint4*)(p + 128);
      breg[2].u = *(const uint4*)(p + 256); breg[3].u = *(const uint4*)(p + 384);
      breg[4].u = *(const uint4*)(p + 512); breg[5].u = *(const uint4*)(p + 640);
      breg[6].u = *(const uint4*)(p + 768); breg[7].u = *(const uint4*)(p + 896);
    }
    // ---- issue adj(tt+2): newest in FIFO -> keeps its 2-step lead ----
    if (tt < 30) {
      const int* p = aptr + (tt + 2) * 32;
      adjv[cur][0] = *(const int4*)p;
      adjv[cur][1] = *(const int4*)(p + 4);
    }
  }

  // ---- per-wave Z partial for each row m: reduce over q ----
  {
    float zz = zp;
    zz += __shfl_down(zz, 32);
    zz += __shfl_down(zz, 16);
    if (ln < 16) zsh[wv][ln] = zz;
  }
  // ---- dump per-wave acc partials; C layout: col = m, row = q*4+reg ----
#pragma unroll
  for (int ft = 0; ft < 8; ++ft) {
#pragma unroll
    for (int reg = 0; reg < 4; ++reg)
      accbuf[wv][q * 4 + reg][ft * 16 + m] = acc[ft][reg];
  }
  __syncthreads();
  if (t < 16) {
    float z = zsh[0][t] + zsh[1][t] + zsh[2][t] + zsh[3][t] +
              zsh[4][t] + zsh[5][t] + zsh[6][t] + zsh[7][t];
    zf[t] = 1.f / z;
  }
  __syncthreads();
  // ---- combine 8 wave-partials + epilogue: out = elu(0.5*h_s + acc/Z) ----
  {
    const int row = t >> 5;        // 0..15
    const int f0 = (t & 31) * 4;   // 0..124
    f32x4 ssum = *(const f32x4*)&accbuf[0][row][f0];
#pragma unroll
    for (int w = 1; w < 8; ++w) ssum += *(const f32x4*)&accbuf[w][row][f0];
    const float invz = zf[row];
    const size_t off = (size_t)(row0 + row) * 128 + f0;
    float4 h = *(const float4*)(HsOut + off);
    float4 o;
    o.x = eluf(fmaf(ssum[0], invz, 0.5f * h.x));
    o.y = eluf(fmaf(ssum[1], invz, 0.5f * h.y));
    o.z = eluf(fmaf(ssum[2], invz, 0.5f * h.z));
    o.w = eluf(fmaf(ssum[3], invz, 0.5f * h.w));
    *(float4*)(HsOut + off) = o;
  }
}

extern "C" void kernel_launch(void* const* d_in, const int* in_sizes, int n_in,
                              void* d_out, int out_size, void* d_ws, size_t ws_size,
                              hipStream_t stream) {
  const float* X   = (const float*)d_in[0];
  const int*   A   = (const int*)d_in[1];
  const float* Ws  = (const float*)d_in[2];
  const float* as_ = (const float*)d_in[3];
  const float* Wn  = (const float*)d_in[4];
  const float* an_ = (const float*)d_in[5];
  float* out = (float*)d_out;  // holds h_s, then final output (in-place epilogue)

  unsigned short* HnT = (unsigned short*)d_ws;       // 128*8192 bf16 = 2 MB (j-block-major)
  float* s = (float*)(HnT + (size_t)128 * NN);       // 8192 f32
  float* n = s + NN;                                 // 8192 f32

  k_proj<<<1024, 256, 0, stream>>>(X, Ws, Wn, as_, an_, out, HnT, s, n);
  k_main<<<512, 512, 0, stream>>>(A, HnT, s, n, out);
}

// Round 3
// 451.946 us; speedup vs baseline: 1.0281x; 1.0172x over previous
//
#include <hip/hip_runtime.h>
#include <math.h>

#define NN 8192
// out = elu(0.5*h_s + (sum_j w_ij h_n_j)/Z_i), w_ij = adj_ij * exp(relu(s_i+n_j))

typedef short short8 __attribute__((ext_vector_type(8)));   // 8 bf16 (4 VGPRs)
typedef float f32x4 __attribute__((ext_vector_type(4)));

__device__ __forceinline__ float eluf(float x) {
  return x > 0.f ? x : (__expf(x) - 1.f);
}
__device__ __forceinline__ unsigned short f2bf(float f) {
  union { float f; unsigned u; } v; v.f = f;
  unsigned r = v.u + 0x7fffu + ((v.u >> 16) & 1u);  // RNE
  return (unsigned short)(r >> 16);
}

// ---------------- Kernel 0: adj (int32 0/1, 256 MB) -> bitmask (8 MB) ----------------
// Pure streaming, no dependent chains: runs at HBM BW. Removes the 256 MB
// latency-critical adj stream from k_main's MFMA pipeline.
// Layout: P[row][j/32] uint, bit b of word = adj[row][seg*32 + b].
__global__ __launch_bounds__(256) void k_pack(const int* __restrict__ A,
                                              unsigned* __restrict__ P) {
  const int t = threadIdx.x;
  const int row = blockIdx.x;  // 8192
  const int4* src = (const int4*)(A + (size_t)row * NN) + t * 8;  // t*32 ints
  int4 v[8];
#pragma unroll
  for (int c = 0; c < 8; ++c) v[c] = src[c];  // 8 loads in flight
  unsigned w = 0;
#pragma unroll
  for (int c = 0; c < 8; ++c) {  // adj in {0,1} -> low bit IS the predicate
    w |= (unsigned)(v[c].x & 1) << (c * 4 + 0);
    w |= (unsigned)(v[c].y & 1) << (c * 4 + 1);
    w |= (unsigned)(v[c].z & 1) << (c * 4 + 2);
    w |= (unsigned)(v[c].w & 1) << (c * 4 + 3);
  }
  P[(size_t)row * 256 + t] = w;
}

// ---------------- Kernel 1: projections + fused s/n reductions ----------------
// 8 rows/block, block 256, grid 1024. HnT output is j-block-major
// [NN/8][128 f][8 j] bf16 so k_main's 8 B-frag loads per 32-j step share ONE
// lane base + imm offsets and coalesce to 256B segments per quad.
__global__ __launch_bounds__(256) void k_proj(const float* __restrict__ X,
                                              const float* __restrict__ Ws,
                                              const float* __restrict__ Wn,
                                              const float* __restrict__ as_,
                                              const float* __restrict__ an_,
                                              float* __restrict__ Hs,
                                              unsigned short* __restrict__ HnT,
                                              float* __restrict__ s_out,
                                              float* __restrict__ n_out) {
  __shared__ float4 lin4[8 * 64];  // 8 rows x 256 f32 = 8 KB
  const int t = threadIdx.x;
  const int i0 = blockIdx.x * 8;
  const float4* Xg = (const float4*)X + (size_t)i0 * 64;
  lin4[t] = Xg[t];
  if (t < 256) lin4[t + 256] = Xg[t + 256];
  __syncthreads();
  const int c = t & 127;
  const int rh = t >> 7;  // 0..1, 4 rows each
  float accs[4], accn[4];
#pragma unroll
  for (int r = 0; r < 4; ++r) { accs[r] = 0.f; accn[r] = 0.f; }
  for (int k = 0; k < 256; k += 4) {
    float ws0 = Ws[(k + 0) * 128 + c], ws1 = Ws[(k + 1) * 128 + c];
    float ws2 = Ws[(k + 2) * 128 + c], ws3 = Ws[(k + 3) * 128 + c];
    float wn0 = Wn[(k + 0) * 128 + c], wn1 = Wn[(k + 1) * 128 + c];
    float wn2 = Wn[(k + 2) * 128 + c], wn3 = Wn[(k + 3) * 128 + c];
#pragma unroll
    for (int r = 0; r < 4; ++r) {
      float4 iv = lin4[(rh * 4 + r) * 64 + (k >> 2)];  // wave-uniform broadcast
      accs[r] = fmaf(iv.x, ws0, accs[r]); accs[r] = fmaf(iv.y, ws1, accs[r]);
      accs[r] = fmaf(iv.z, ws2, accs[r]); accs[r] = fmaf(iv.w, ws3, accs[r]);
      accn[r] = fmaf(iv.x, wn0, accn[r]); accn[r] = fmaf(iv.y, wn1, accn[r]);
      accn[r] = fmaf(iv.z, wn2, accn[r]); accn[r] = fmaf(iv.w, wn3, accn[r]);
    }
  }
  // Hs fp32 out
#pragma unroll
  for (int r = 0; r < 4; ++r)
    Hs[(size_t)(i0 + rh * 4 + r) * 128 + c] = accs[r];
  // HnT bf16 out, j-block-major: elem(jb=j/8, f, ji=j%8) at jb*1024 + f*8 + ji.
  {
    union { unsigned short us[4]; ushort4 u4; } pk;
#pragma unroll
    for (int r = 0; r < 4; ++r) pk.us[r] = f2bf(accn[r]);
    *(ushort4*)(HnT + (size_t)blockIdx.x * 1024 + c * 8 + rh * 4) = pk.u4;
  }
  // ---- fused reductions: s[j] = sum_f Hs[j][f]*a_s[f], n likewise ----
  float* red = (float*)lin4;  // 8 x 128 f32 = 4 KB
  const int wv = t >> 6, ln = t & 63;
  __syncthreads();
  {
    float av = as_[c];
#pragma unroll
    for (int r = 0; r < 4; ++r) red[(rh * 4 + r) * 128 + c] = accs[r] * av;
  }
  __syncthreads();
#pragma unroll
  for (int h = 0; h < 2; ++h) {
    int row = wv * 2 + h;
    float p = red[row * 128 + ln] + red[row * 128 + 64 + ln];
#pragma unroll
    for (int off = 32; off >= 1; off >>= 1) p += __shfl_down(p, off);
    if (ln == 0) s_out[i0 + row] = p;
  }
  __syncthreads();
  {
    float av = an_[c];
#pragma unroll
    for (int r = 0; r < 4; ++r) red[(rh * 4 + r) * 128 + c] = accn[r] * av;
  }
  __syncthreads();
#pragma unroll
  for (int h = 0; h < 2; ++h) {
    int row = wv * 2 + h;
    float p = red[row * 128 + ln] + red[row * 128 + 64 + ln];
#pragma unroll
    for (int off = 32; off >= 1; off >>= 1) p += __shfl_down(p, off);
    if (ln == 0) n_out[i0 + row] = p;
  }
}

// ---------------- Kernel 2 (bits path): attention GEMM + softmax + elu --------
// Barrier-free main loop: 16 rows/block, block 512 (8 waves), grid 512.
// Each wave owns a private 1024-wide j-range (32 steps of K=32). adj arrives
// as a 1-dword broadcast bit-word per step (L3-resident 8 MB bitmask, 2-step
// lead); nv has 2-step lead; breg (HnT, L2-resident) 1-step lead.
__global__ __launch_bounds__(512, 4) void k_main_bits(const unsigned* __restrict__ Pk,
                                                      const unsigned short* __restrict__ HnT,
                                                      const float* __restrict__ sv_g,
                                                      const float* __restrict__ nv_g,
                                                      float* __restrict__ HsOut) {
  __shared__ float accbuf[8][16][128];  // 64 KB: per-wave 16x128 partials
  __shared__ float zsh[8][16];
  __shared__ float zf[16];

  const int t = threadIdx.x;
  const int wv = t >> 6;   // wave 0..7 = j-partition
  const int ln = t & 63;
  const int q = ln >> 4;   // quad -> k-slice within K=32
  const int m = ln & 15;   // A row / B col / C col
  const int row0 = blockIdx.x * 16;

  const float sm = sv_g[row0 + m];
  const int jbase = wv * 1024 + q * 8;
  const float* nptr = nv_g + jbase;
  // bit-words: P[row][j/32]; this lane's word for step tt is Pp[tt]
  const unsigned* Pp = Pk + (size_t)(row0 + m) * 256 + wv * 32;
  // HnT elem(jb, f, ji) at jb*1024 + f*8 + ji ; lane base: jb = wv*128 + q, f = m
  const unsigned short* bptr = HnT + ((size_t)(wv * 128 + q) * 128 + m) * 8;

  f32x4 acc[8];
#pragma unroll
  for (int ft = 0; ft < 8; ++ft) acc[ft] = (f32x4){0.f, 0.f, 0.f, 0.f};
  float zp = 0.f;

  float4 nvv[2][2];
  unsigned bv[2];
  union Breg { uint4 u; short8 s; };
  Breg breg[8];

  // prolog: nv(0), nv(1), bits(0), bits(1), breg(0)
  nvv[0][0] = *(const float4*)(nptr);      nvv[0][1] = *(const float4*)(nptr + 4);
  nvv[1][0] = *(const float4*)(nptr + 32); nvv[1][1] = *(const float4*)(nptr + 36);
  bv[0] = Pp[0];
  bv[1] = Pp[1];
  breg[0].u = *(const uint4*)(bptr);       breg[1].u = *(const uint4*)(bptr + 128);
  breg[2].u = *(const uint4*)(bptr + 256); breg[3].u = *(const uint4*)(bptr + 384);
  breg[4].u = *(const uint4*)(bptr + 512); breg[5].u = *(const uint4*)(bptr + 640);
  breg[6].u = *(const uint4*)(bptr + 768); breg[7].u = *(const uint4*)(bptr + 896);

#pragma unroll 2
  for (int tt = 0; tt < 32; ++tt) {
    const int cur = tt & 1;
    // ---- A-frag: w for rows m, j = jbase + tt*32 + q*8 .. +7 ----
    short8 fr;
    {
      float nvl[8] = {nvv[cur][0].x, nvv[cur][0].y, nvv[cur][0].z, nvv[cur][0].w,
                      nvv[cur][1].x, nvv[cur][1].y, nvv[cur][1].z, nvv[cur][1].w};
      const unsigned byte = (bv[cur] >> (q * 8)) & 0xffu;
#pragma unroll
      for (int k = 0; k < 8; ++k) {
        float w = ((byte >> k) & 1u) ? __expf(fmaxf(sm + nvl[k], 0.f)) : 0.f;
        zp += w;
        fr[k] = (short)f2bf(w);
      }
    }
    // ---- issue nv(tt+2), bits(tt+2): 2-step lead ----
    if (tt < 30) {
      const float* p = nptr + (tt + 2) * 32;
      nvv[cur][0] = *(const float4*)p;
      nvv[cur][1] = *(const float4*)(p + 4);
      bv[cur] = Pp[tt + 2];
    }
    // ---- MFMA: consumes breg(tt); prefetches stay in flight ----
    __builtin_amdgcn_s_setprio(1);
    acc[0] = __builtin_amdgcn_mfma_f32_16x16x32_bf16(fr, breg[0].s, acc[0], 0, 0, 0);
    acc[1] = __builtin_amdgcn_mfma_f32_16x16x32_bf16(fr, breg[1].s, acc[1], 0, 0, 0);
    acc[2] = __builtin_amdgcn_mfma_f32_16x16x32_bf16(fr, breg[2].s, acc[2], 0, 0, 0);
    acc[3] = __builtin_amdgcn_mfma_f32_16x16x32_bf16(fr, breg[3].s, acc[3], 0, 0, 0);
    acc[4] = __builtin_amdgcn_mfma_f32_16x16x32_bf16(fr, breg[4].s, acc[4], 0, 0, 0);
    acc[5] = __builtin_amdgcn_mfma_f32_16x16x32_bf16(fr, breg[5].s, acc[5], 0, 0, 0);
    acc[6] = __builtin_amdgcn_mfma_f32_16x16x32_bf16(fr, breg[6].s, acc[6], 0, 0, 0);
    acc[7] = __builtin_amdgcn_mfma_f32_16x16x32_bf16(fr, breg[7].s, acc[7], 0, 0, 0);
    __builtin_amdgcn_s_setprio(0);
    // ---- issue breg(tt+1): 8 f-tiles, one base + imm offsets ----
    if (tt < 31) {
      const unsigned short* p = bptr + (size_t)(tt + 1) * 4096;  // +4 j-blocks
      breg[0].u = *(const uint4*)(p);       breg[1].u = *(const uint4*)(p + 128);
      breg[2].u = *(const uint4*)(p + 256); breg[3].u = *(const uint4*)(p + 384);
      breg[4].u = *(const uint4*)(p + 512); breg[5].u = *(const uint4*)(p + 640);
      breg[6].u = *(const uint4*)(p + 768); breg[7].u = *(const uint4*)(p + 896);
    }
  }

  // ---- per-wave Z partial for each row m: reduce over q ----
  {
    float zz = zp;
    zz += __shfl_down(zz, 32);
    zz += __shfl_down(zz, 16);
    if (ln < 16) zsh[wv][ln] = zz;
  }
  // ---- dump per-wave acc partials; C layout: col = m, row = q*4+reg ----
#pragma unroll
  for (int ft = 0; ft < 8; ++ft) {
#pragma unroll
    for (int reg = 0; reg < 4; ++reg)
      accbuf[wv][q * 4 + reg][ft * 16 + m] = acc[ft][reg];
  }
  __syncthreads();
  if (t < 16) {
    float z = zsh[0][t] + zsh[1][t] + zsh[2][t] + zsh[3][t] +
              zsh[4][t] + zsh[5][t] + zsh[6][t] + zsh[7][t];
    zf[t] = 1.f / z;
  }
  __syncthreads();
  // ---- combine 8 wave-partials + epilogue: out = elu(0.5*h_s + acc/Z) ----
  {
    const int row = t >> 5;        // 0..15
    const int f0 = (t & 31) * 4;   // 0..124
    f32x4 ssum = *(const f32x4*)&accbuf[0][row][f0];
#pragma unroll
    for (int w = 1; w < 8; ++w) ssum += *(const f32x4*)&accbuf[w][row][f0];
    const float invz = zf[row];
    const size_t off = (size_t)(row0 + row) * 128 + f0;
    float4 h = *(const float4*)(HsOut + off);
    float4 o;
    o.x = eluf(fmaf(ssum[0], invz, 0.5f * h.x));
    o.y = eluf(fmaf(ssum[1], invz, 0.5f * h.y));
    o.z = eluf(fmaf(ssum[2], invz, 0.5f * h.z));
    o.w = eluf(fmaf(ssum[3], invz, 0.5f * h.w));
    *(float4*)(HsOut + off) = o;
  }
}

// ---------------- Kernel 2 (fallback, R1-verified): reads A directly -----------
__global__ __launch_bounds__(512, 4) void k_main_adj(const int* __restrict__ A,
                                                     const unsigned short* __restrict__ HnT,
                                                     const float* __restrict__ sv_g,
                                                     const float* __restrict__ nv_g,
                                                     float* __restrict__ HsOut) {
  __shared__ float accbuf[8][16][128];
  __shared__ float zsh[8][16];
  __shared__ float zf[16];

  const int t = threadIdx.x;
  const int wv = t >> 6;
  const int ln = t & 63;
  const int q = ln >> 4;
  const int m = ln & 15;
  const int row0 = blockIdx.x * 16;

  const float sm = sv_g[row0 + m];
  const int jbase = wv * 1024 + q * 8;
  const int* aptr = A + (size_t)(row0 + m) * NN + jbase;
  const float* nptr = nv_g + jbase;
  const unsigned short* bptr = HnT + ((size_t)(wv * 128 + q) * 128 + m) * 8;

  f32x4 acc[8];
#pragma unroll
  for (int ft = 0; ft < 8; ++ft) acc[ft] = (f32x4){0.f, 0.f, 0.f, 0.f};
  float zp = 0.f;

  int4 adjv[2][2];
  float4 nvv[2][2];
  union Breg { uint4 u; short8 s; };
  Breg breg[8];

  adjv[0][0] = *(const int4*)(aptr);       adjv[0][1] = *(const int4*)(aptr + 4);
  adjv[1][0] = *(const int4*)(aptr + 32);  adjv[1][1] = *(const int4*)(aptr + 36);
  nvv[0][0] = *(const float4*)(nptr);      nvv[0][1] = *(const float4*)(nptr + 4);
  breg[0].u = *(const uint4*)(bptr);       breg[1].u = *(const uint4*)(bptr + 128);
  breg[2].u = *(const uint4*)(bptr + 256); breg[3].u = *(const uint4*)(bptr + 384);
  breg[4].u = *(const uint4*)(bptr + 512); breg[5].u = *(const uint4*)(bptr + 640);
  breg[6].u = *(const uint4*)(bptr + 768); breg[7].u = *(const uint4*)(bptr + 896);

#pragma unroll 2
  for (int tt = 0; tt < 32; ++tt) {
    const int cur = tt & 1;
    short8 fr;
    {
      float nvl[8] = {nvv[cur][0].x, nvv[cur][0].y, nvv[cur][0].z, nvv[cur][0].w,
                      nvv[cur][1].x, nvv[cur][1].y, nvv[cur][1].z, nvv[cur][1].w};
      int av[8] = {adjv[cur][0].x, adjv[cur][0].y, adjv[cur][0].z, adjv[cur][0].w,
                   adjv[cur][1].x, adjv[cur][1].y, adjv[cur][1].z, adjv[cur][1].w};
#pragma unroll
      for (int k = 0; k < 8; ++k) {
        float w = av[k] > 0 ? __expf(fmaxf(sm + nvl[k], 0.f)) : 0.f;
        zp += w;
        fr[k] = (short)f2bf(w);
      }
    }
    if (tt < 31) {
      const float* p = nptr + (tt + 1) * 32;
      nvv[cur ^ 1][0] = *(const float4*)p;
      nvv[cur ^ 1][1] = *(const float4*)(p + 4);
    }
    __builtin_amdgcn_s_setprio(1);
    acc[0] = __builtin_amdgcn_mfma_f32_16x16x32_bf16(fr, breg[0].s, acc[0], 0, 0, 0);
    acc[1] = __builtin_amdgcn_mfma_f32_16x16x32_bf16(fr, breg[1].s, acc[1], 0, 0, 0);
    acc[2] = __builtin_amdgcn_mfma_f32_16x16x32_bf16(fr, breg[2].s, acc[2], 0, 0, 0);
    acc[3] = __builtin_amdgcn_mfma_f32_16x16x32_bf16(fr, breg[3].s, acc[3], 0, 0, 0);
    acc[4] = __builtin_amdgcn_mfma_f32_16x16x32_bf16(fr, breg[4].s, acc[4], 0, 0, 0);
    acc[5] = __builtin_amdgcn_mfma_f32_16x16x32_bf16(fr, breg[5].s, acc[5], 0, 0, 0);
    acc[6] = __builtin_amdgcn_mfma_f32_16x16x32_bf16(fr, breg[6].s, acc[6], 0, 0, 0);
    acc[7] = __builtin_amdgcn_mfma_f32_16x16x32_bf16(fr, breg[7].s, acc[7], 0, 0, 0);
    __builtin_amdgcn_s_setprio(0);
    if (tt < 31) {
      const unsigned short* p = bptr + (size_t)(tt + 1) * 4096;
      breg[0].u = *(const uint4*)(p);       breg[1].u = *(const uint4*)(p + 128);
      breg[2].u = *(const uint4*)(p + 256); breg[3].u = *(const uint4*)(p + 384);
      breg[4].u = *(const uint4*)(p + 512); breg[5].u = *(const uint4*)(p + 640);
      breg[6].u = *(const uint4*)(p + 768); breg[7].u = *(const uint4*)(p + 896);
    }
    if (tt < 30) {
      const int* p = aptr + (tt + 2) * 32;
      adjv[cur][0] = *(const int4*)p;
      adjv[cur][1] = *(const int4*)(p + 4);
    }
  }

  {
    float zz = zp;
    zz += __shfl_down(zz, 32);
    zz += __shfl_down(zz, 16);
    if (ln < 16) zsh[wv][ln] = zz;
  }
#pragma unroll
  for (int ft = 0; ft < 8; ++ft) {
#pragma unroll
    for (int reg = 0; reg < 4; ++reg)
      accbuf[wv][q * 4 + reg][ft * 16 + m] = acc[ft][reg];
  }
  __syncthreads();
  if (t < 16) {
    float z = zsh[0][t] + zsh[1][t] + zsh[2][t] + zsh[3][t] +
              zsh[4][t] + zsh[5][t] + zsh[6][t] + zsh[7][t];
    zf[t] = 1.f / z;
  }
  __syncthreads();
  {
    const int row = t >> 5;
    const int f0 = (t & 31) * 4;
    f32x4 ssum = *(const f32x4*)&accbuf[0][row][f0];
#pragma unroll
    for (int w = 1; w < 8; ++w) ssum += *(const f32x4*)&accbuf[w][row][f0];
    const float invz = zf[row];
    const size_t off = (size_t)(row0 + row) * 128 + f0;
    float4 h = *(const float4*)(HsOut + off);
    float4 o;
    o.x = eluf(fmaf(ssum[0], invz, 0.5f * h.x));
    o.y = eluf(fmaf(ssum[1], invz, 0.5f * h.y));
    o.z = eluf(fmaf(ssum[2], invz, 0.5f * h.z));
    o.w = eluf(fmaf(ssum[3], invz, 0.5f * h.w));
    *(float4*)(HsOut + off) = o;
  }
}

extern "C" void kernel_launch(void* const* d_in, const int* in_sizes, int n_in,
                              void* d_out, int out_size, void* d_ws, size_t ws_size,
                              hipStream_t stream) {
  const float* X   = (const float*)d_in[0];
  const int*   A   = (const int*)d_in[1];
  const float* Ws  = (const float*)d_in[2];
  const float* as_ = (const float*)d_in[3];
  const float* Wn  = (const float*)d_in[4];
  const float* an_ = (const float*)d_in[5];
  float* out = (float*)d_out;  // holds h_s, then final output (in-place epilogue)

  unsigned short* HnT = (unsigned short*)d_ws;       // 2 MB (j-block-major)
  float* s = (float*)(HnT + (size_t)128 * NN);       // 8192 f32
  float* n = s + NN;                                 // 8192 f32
  unsigned* P = (unsigned*)(n + NN);                 // 8192*256 uint = 8 MB bitmask

  const size_t base_need = (size_t)128 * NN * 2 + (size_t)2 * NN * 4;
  const size_t bits_need = base_need + (size_t)NN * 256 * 4;

  k_proj<<<1024, 256, 0, stream>>>(X, Ws, Wn, as_, an_, out, HnT, s, n);
  if (ws_size >= bits_need) {
    k_pack<<<8192, 256, 0, stream>>>(A, P);
    k_main_bits<<<512, 512, 0, stream>>>(P, HnT, s, n, out);
  } else {
    k_main_adj<<<512, 512, 0, stream>>>(A, HnT, s, n, out);
  }
}